// Round 5
// baseline (101.675 us; speedup 1.0000x reference)
//
#include <hip/hip_runtime.h>
#include <hip/hip_bf16.h>

// Problem constants
#define CCH   256        // channels C
#define NG    16         // groups
#define GCN   16         // group channels
#define CRD   64         // reduced channels C/R
#define HH    56
#define WWD   56
#define HWP   3136       // 56*56
#define BB    8
#define NPIX  25088      // B*H*W
#define K2    49
#define O2N   784        // K2 * NG
#define EPSV  1e-5f

#define XROWS 62         // 56 + 2*3 padded rows
#define XRW   64         // padded row width (16B-aligned rows; cols 0..61 valid)
#define CHSTR 3968       // 62*64 floats per (b,ch) plane

typedef unsigned short ushort_t;
typedef __attribute__((ext_vector_type(8))) short bf16x8;
typedef __attribute__((ext_vector_type(4))) float f32x4;

// workspace layout (float units)
#define XP_OFF   0                         // fp32 padded x [b][ch][62][64]
#define XP2_SZ   8126464                   // 8*256*3968
#define XT_OFF   8126464                   // x_t bf16 [pix][256]: 6,422,528 shorts
#define YT_OFF   11337728                  // y_t bf16 [pix][64]: 1,605,632 shorts
#define W1B_OFF  12140544                  // W1 bf16 [64][256]
#define W2B_OFF  12148736                  // W2 bf16 padded [800][64]
#define B2P_OFF  12174336                  // b2 padded: 800 floats
#define BNS_OFF  12175136                  // 64
#define BNT_OFF  12175200                  // 64
// end = 12,175,264 floats = 48.7 MB

__device__ __forceinline__ ushort_t f2bf(float f) {
    unsigned u = __builtin_bit_cast(unsigned, f);
    return (ushort_t)((u + 0x7FFFu + ((u >> 16) & 1u)) >> 16);   // RNE
}

// ---------------------------------------------------------------------------
// prep: zero xp; W1,W2(bf16, W2 padded to 800 rows); b2 padded; BN fold
// ---------------------------------------------------------------------------
__global__ __launch_bounds__(256) void prep_kernel(const float* __restrict__ W1,
                                                   const float* __restrict__ b1,
                                                   const float* __restrict__ gamma,
                                                   const float* __restrict__ beta,
                                                   const float* __restrict__ mean,
                                                   const float* __restrict__ var,
                                                   const float* __restrict__ W2,
                                                   const float* __restrict__ b2,
                                                   float* __restrict__ ws) {
    int gid = blockIdx.x * 256 + threadIdx.x;
    int stride = gridDim.x * 256;
    uint4 z = {0u, 0u, 0u, 0u};
    uint4* xpv = (uint4*)(ws + XP_OFF);
    for (int e = gid; e < XP2_SZ / 4; e += stride) xpv[e] = z;

    ushort_t* w1b = (ushort_t*)(ws + W1B_OFF);
    if (gid < CRD * CCH) w1b[gid] = f2bf(W1[gid]);               // [o][c]
    ushort_t* w2b = (ushort_t*)(ws + W2B_OFF);
    if (gid < 800 * CRD) w2b[gid] = (gid < O2N * CRD) ? f2bf(W2[gid]) : (ushort_t)0;
    if (gid < 800) ws[B2P_OFF + gid] = (gid < O2N) ? b2[gid] : 0.f;
    if (gid < CRD) {
        float s = gamma[gid] * rsqrtf(var[gid] + EPSV);
        ws[BNS_OFF + gid] = s;
        ws[BNT_OFF + gid] = (b1[gid] - mean[gid]) * s + beta[gid];
    }
}

// ---------------------------------------------------------------------------
// pack_x: read x ONCE -> x_t[pix][256] bf16 (LDS transpose) + xp fp32 interior
// ---------------------------------------------------------------------------
__global__ __launch_bounds__(256) void pack_x(const float* __restrict__ x,
                                              float* __restrict__ ws) {
    __shared__ ushort_t st[64 * 270];      // pad 256->270 shorts (odd-word row stride)
    int tid = threadIdx.x;
    int b = blockIdx.y, hw0 = blockIdx.x * 64;
    int lane = tid & 63, c4 = tid >> 6;
    int hw = hw0 + lane;
    int h = hw / WWD, w = hw - h * WWD;
    const float* xb = x + (b * CCH) * HWP + hw;
    float* xpd = ws + XP_OFF + (size_t)(b * CCH) * CHSTR + (h + 3) * XRW + (w + 3);
#pragma unroll 8
    for (int i = 0; i < 64; ++i) {
        int c = i * 4 + c4;
        float v = xb[c * HWP];
        st[lane * 270 + c] = f2bf(v);
        xpd[c * CHSTR] = v;
    }
    __syncthreads();
    const unsigned* stu = (const unsigned*)st;           // row stride 135 words
    unsigned* xtu = (unsigned*)(ws + XT_OFF);            // x_t rows: 128 words
    int rowg = b * HWP + hw0;
#pragma unroll
    for (int k = 0; k < 32; ++k) {
        int idx = k * 256 + tid;
        int row = idx >> 7, c2 = idx & 127;
        xtu[(rowg + row) * 128 + c2] = stu[row * 135 + c2];
    }
}

// ---------------------------------------------------------------------------
// conv1 (MFMA bf16): y_t[pix][64] = relu(bns[o]*(x_t @ W1^T)[o][pix] + bnt[o])
// ---------------------------------------------------------------------------
__global__ __launch_bounds__(256) void conv1_mfma(float* __restrict__ ws) {
    const ushort_t* xt  = (const ushort_t*)(ws + XT_OFF);
    const ushort_t* w1b = (const ushort_t*)(ws + W1B_OFF);
    const float* bns = ws + BNS_OFF;
    const float* bnt = ws + BNT_OFF;
    ushort_t* yt = (ushort_t*)(ws + YT_OFF);

    int tid = threadIdx.x, lane = tid & 63, wv = tid >> 6;
    int lr = lane & 15, lg = lane >> 4;
    int ot = blockIdx.x;                                  // 0..3
    int pixbase = blockIdx.y * 128 + wv * 32;

    const bf16x8* ap = (const bf16x8*)(w1b + (ot * 16 + lr) * CCH + lg * 8);
    bf16x8 a[8];
#pragma unroll
    for (int ks = 0; ks < 8; ++ks) a[ks] = ap[ks * 4];

    f32x4 acc[2] = {{0.f,0.f,0.f,0.f}, {0.f,0.f,0.f,0.f}};
#pragma unroll
    for (int f = 0; f < 2; ++f) {
        const bf16x8* bp = (const bf16x8*)(xt + (pixbase + f * 16 + lr) * CCH + lg * 8);
#pragma unroll
        for (int ks = 0; ks < 8; ++ks)
            acc[f] = __builtin_amdgcn_mfma_f32_16x16x32_bf16(a[ks], bp[ks * 4], acc[f], 0, 0, 0);
    }

    int o0 = ot * 16 + lg * 4;
    float4 s4 = *(const float4*)(bns + o0);
    float4 t4 = *(const float4*)(bnt + o0);
#pragma unroll
    for (int f = 0; f < 2; ++f) {
        int pix = pixbase + f * 16 + lr;
        union { ushort_t u[4]; uint2 v; } pk;
        pk.u[0] = f2bf(fmaxf(acc[f][0] * s4.x + t4.x, 0.f));
        pk.u[1] = f2bf(fmaxf(acc[f][1] * s4.y + t4.y, 0.f));
        pk.u[2] = f2bf(fmaxf(acc[f][2] * s4.z + t4.z, 0.f));
        pk.u[3] = f2bf(fmaxf(acc[f][3] * s4.w + t4.w, 0.f));
        *(uint2*)(yt + pix * CRD + o0) = pk.v;
    }
}

// ---------------------------------------------------------------------------
// invol_fused: per block (h0-tile of 4 rows, g, b):
//   A) stage y slice [224 pix][64] bf16 into swizzled LDS
//   B) MFMA: wgt tile (49 o2 x 224 pix) = W2[g-slice] @ y^T + b2 (in regs)
//   B2) scatter wgt -> LDS f32  wl[k][wb][ (r^(wb&3))*4 + t ]
//   C) involution: lane=(c4,wb); 1 ch x 4 rows x 4 w per thread;
//      x via ALIGNED dwordx4 from 64-wide padded rows, rolling 5-row window
// ---------------------------------------------------------------------------
__global__ __launch_bounds__(256, 3) void invol_fused(const float* __restrict__ ws,
                                                      float* __restrict__ out) {
    __shared__ uint4 lds4[2744];           // 43904 B (y stage 28672 B; wl f32 43904 B)
    unsigned char* ldsb = (unsigned char*)lds4;

    int h0t = blockIdx.x;                  // 0..13
    int g   = blockIdx.y;
    int b   = blockIdx.z;
    int tid = threadIdx.x, lane = tid & 63, wv = tid >> 6;
    int lr = lane & 15, lg = lane >> 4;
    int pix0 = b * HWP + h0t * 224;

    // ---- Phase A: stage y (224 rows x 128 B), st_16x32-style swizzle
    const uint4* ysrc = (const uint4*)((const ushort_t*)(ws + YT_OFF) + (size_t)pix0 * CRD);
    for (int i = tid; i < 1792; i += 256) {
        int row = i >> 3;
        unsigned off = (unsigned)(i * 16) ^ (unsigned)((row & 7) << 4);
        *(uint4*)(ldsb + off) = ysrc[i];
    }
    __syncthreads();

    // ---- Phase B: MFMA. wave wv = o2-tile (rows wv*16..+15 of g-slice)
    const ushort_t* w2b = (const ushort_t*)(ws + W2B_OFF);
    const bf16x8* ar = (const bf16x8*)(w2b + (g * K2 + wv * 16 + lr) * CRD);
    bf16x8 a0 = ar[lg], a1 = ar[4 + lg];   // kstep 0 / 1

    f32x4 acc[14];
#pragma unroll
    for (int pt = 0; pt < 14; ++pt) acc[pt] = (f32x4){0.f, 0.f, 0.f, 0.f};
#pragma unroll
    for (int pt = 0; pt < 14; ++pt) {
        int row = pt * 16 + lr;
        unsigned sw = (unsigned)((row & 7) << 4);
        uint4 b0 = *(const uint4*)(ldsb + ((unsigned)(row * 128 + lg * 16) ^ sw));
        uint4 b1 = *(const uint4*)(ldsb + ((unsigned)(row * 128 + 64 + lg * 16) ^ sw));
        acc[pt] = __builtin_amdgcn_mfma_f32_16x16x32_bf16(a0, __builtin_bit_cast(bf16x8, b0), acc[pt], 0, 0, 0);
        acc[pt] = __builtin_amdgcn_mfma_f32_16x16x32_bf16(a1, __builtin_bit_cast(bf16x8, b1), acc[pt], 0, 0, 0);
    }
    __syncthreads();                        // y reads done; reuse LDS for wl

    // ---- Phase B2: wgt -> wl f32, index k*224 + wb*16 + (r^(wb&3))*4 + t
    float* wlf = (float*)ldsb;
    const float* b2p = ws + B2P_OFF;
    float b2v[4];
#pragma unroll
    for (int j = 0; j < 4; ++j)
        b2v[j] = b2p[g * K2 + wv * 16 + lg * 4 + j];   // padded, safe for k>=49
#pragma unroll
    for (int pt = 0; pt < 14; ++pt) {
        int pix = pt * 16 + lr;
        int r = pix / WWD;
        int w = pix - r * WWD;
        int wb = w >> 2, t = w & 3;
        int base = wb * 16 + ((r ^ (wb & 3)) << 2) + t;
#pragma unroll
        for (int j = 0; j < 4; ++j) {
            int k = wv * 16 + lg * 4 + j;
            if (k < K2)
                wlf[k * 224 + base] = acc[pt][j] + b2v[j];
        }
    }
    __syncthreads();

    // ---- Phase C: lane = (c4, wb). ch = g*16 + wv*4 + c4; outputs 4r x 4w.
    int c4 = lane >> 4, wb = lane & 15;
    if (wb < 14) {
        int ch = g * GCN + wv * 4 + c4;
        const float* xrb = ws + XP_OFF + (size_t)(b * CCH + ch) * CHSTR
                         + (h0t * 4) * XRW + wb * 4;

        float xw[5][12];                   // rolling window: padded row n in slot n%5
#pragma unroll
        for (int n = 0; n < 4; ++n) {
            __builtin_memcpy(&xw[n][0], xrb + n * XRW, 16);
            __builtin_memcpy(&xw[n][4], xrb + n * XRW + 4, 16);
            __builtin_memcpy(&xw[n][8], xrb + n * XRW + 8, 16);
        }

        float acc2[4][4];
#pragma unroll
        for (int r = 0; r < 4; ++r)
#pragma unroll
            for (int t = 0; t < 4; ++t) acc2[r][t] = 0.f;

        int swz = (wb & 3) << 2;
#pragma unroll
        for (int ki = 0; ki < 7; ++ki) {
            if (ki < 6) {                  // prefetch row ki+4 into slot (ki+4)%5
                int n = ki + 4;
                float* dst = &xw[n % 5][0];
                __builtin_memcpy(dst,     xrb + n * XRW, 16);
                __builtin_memcpy(dst + 4, xrb + n * XRW + 4, 16);
                __builtin_memcpy(dst + 8, xrb + n * XRW + 8, 16);
            }
#pragma unroll
            for (int dj = 0; dj < 7; ++dj) {
                int k = ki * 7 + dj;
                const float* kb = wlf + k * 224 + wb * 16;
                f32x4 wr0 = *(const f32x4*)(kb + ((0 << 2) ^ swz));
                f32x4 wr1 = *(const f32x4*)(kb + ((1 << 2) ^ swz));
                f32x4 wr2 = *(const f32x4*)(kb + ((2 << 2) ^ swz));
                f32x4 wr3 = *(const f32x4*)(kb + ((3 << 2) ^ swz));
#pragma unroll
                for (int t = 0; t < 4; ++t) {
                    acc2[0][t] = fmaf(xw[(ki + 0) % 5][t + dj], wr0[t], acc2[0][t]);
                    acc2[1][t] = fmaf(xw[(ki + 1) % 5][t + dj], wr1[t], acc2[1][t]);
                    acc2[2][t] = fmaf(xw[(ki + 2) % 5][t + dj], wr2[t], acc2[2][t]);
                    acc2[3][t] = fmaf(xw[(ki + 3) % 5][t + dj], wr3[t], acc2[3][t]);
                }
            }
        }

        float* ob = out + (size_t)(b * CCH + ch) * HWP + (h0t * 4) * WWD + wb * 4;
#pragma unroll
        for (int r = 0; r < 4; ++r) {
            float4 v = {acc2[r][0], acc2[r][1], acc2[r][2], acc2[r][3]};
            *(float4*)(ob + r * WWD) = v;
        }
    }
}

// ---------------------------------------------------------------------------
extern "C" void kernel_launch(void* const* d_in, const int* in_sizes, int n_in,
                              void* d_out, int out_size, void* d_ws, size_t ws_size,
                              hipStream_t stream) {
    const float* x     = (const float*)d_in[0];
    const float* W1    = (const float*)d_in[1];
    const float* b1    = (const float*)d_in[2];
    const float* gamma = (const float*)d_in[3];
    const float* beta  = (const float*)d_in[4];
    const float* mean  = (const float*)d_in[5];
    const float* var   = (const float*)d_in[6];
    const float* W2    = (const float*)d_in[7];
    const float* b2    = (const float*)d_in[8];

    float* ws  = (float*)d_ws;
    float* out = (float*)d_out;

    prep_kernel<<<2048, 256, 0, stream>>>(W1, b1, gamma, beta, mean, var, W2, b2, ws);
    pack_x<<<dim3(HWP / 64, BB), 256, 0, stream>>>(x, ws);
    conv1_mfma<<<dim3(4, NPIX / 128), 256, 0, stream>>>(ws);
    invol_fused<<<dim3(14, NG, BB), 256, 0, stream>>>(ws, out);
}

// Round 6
// 92.969 us; speedup vs baseline: 1.0936x; 1.0936x over previous
//
#include <hip/hip_runtime.h>
#include <hip/hip_bf16.h>

// Problem constants
#define CCH   256        // channels C
#define NG    16         // groups
#define GCN   16         // group channels
#define CRD   64         // reduced channels C/R
#define HH    56
#define WWD   56
#define HWP   3136       // 56*56
#define BB    8
#define NPIX  25088      // B*H*W
#define K2    49
#define O2N   784        // K2 * NG
#define EPSV  1e-5f

#define XROWS 62         // 56 + 2*3 padded rows
#define XRW   64         // padded row width (16B-aligned rows; cols 0..61 valid)
#define CHSTR 3968       // 62*64 floats per (b,ch) plane

typedef unsigned short ushort_t;
typedef __attribute__((ext_vector_type(8))) short bf16x8;
typedef __attribute__((ext_vector_type(4))) float f32x4;

// workspace layout (float units)
#define XP_OFF   0                         // fp32 padded x [b][ch][62][64]
#define XP2_SZ   8126464                   // 8*256*3968
#define XT_OFF   8126464                   // x_t bf16 [pix][256]: 6,422,528 shorts
#define YT_OFF   11337728                  // y_t bf16 [pix][64]: 1,605,632 shorts
#define W1B_OFF  12140544                  // W1 bf16 [64][256]
#define W2B_OFF  12148736                  // W2 bf16 padded [800][64]
#define B2P_OFF  12174336                  // b2 padded: 800 floats
#define BNS_OFF  12175136                  // 64
#define BNT_OFF  12175200                  // 64
// end = 12,175,264 floats = 48.7 MB

__device__ __forceinline__ ushort_t f2bf(float f) {
    unsigned u = __builtin_bit_cast(unsigned, f);
    return (ushort_t)((u + 0x7FFFu + ((u >> 16) & 1u)) >> 16);   // RNE
}

// ---------------------------------------------------------------------------
// prep: zero xp; W1,W2(bf16, W2 padded to 800 rows); b2 padded; BN fold
// ---------------------------------------------------------------------------
__global__ __launch_bounds__(256) void prep_kernel(const float* __restrict__ W1,
                                                   const float* __restrict__ b1,
                                                   const float* __restrict__ gamma,
                                                   const float* __restrict__ beta,
                                                   const float* __restrict__ mean,
                                                   const float* __restrict__ var,
                                                   const float* __restrict__ W2,
                                                   const float* __restrict__ b2,
                                                   float* __restrict__ ws) {
    int gid = blockIdx.x * 256 + threadIdx.x;
    int stride = gridDim.x * 256;
    uint4 z = {0u, 0u, 0u, 0u};
    uint4* xpv = (uint4*)(ws + XP_OFF);
    for (int e = gid; e < XP2_SZ / 4; e += stride) xpv[e] = z;

    ushort_t* w1b = (ushort_t*)(ws + W1B_OFF);
    if (gid < CRD * CCH) w1b[gid] = f2bf(W1[gid]);               // [o][c]
    ushort_t* w2b = (ushort_t*)(ws + W2B_OFF);
    if (gid < 800 * CRD) w2b[gid] = (gid < O2N * CRD) ? f2bf(W2[gid]) : (ushort_t)0;
    if (gid < 800) ws[B2P_OFF + gid] = (gid < O2N) ? b2[gid] : 0.f;
    if (gid < CRD) {
        float s = gamma[gid] * rsqrtf(var[gid] + EPSV);
        ws[BNS_OFF + gid] = s;
        ws[BNT_OFF + gid] = (b1[gid] - mean[gid]) * s + beta[gid];
    }
}

// ---------------------------------------------------------------------------
// pack_x: read x ONCE -> x_t[pix][256] bf16 (LDS transpose) + xp fp32 interior
// ---------------------------------------------------------------------------
__global__ __launch_bounds__(256) void pack_x(const float* __restrict__ x,
                                              float* __restrict__ ws) {
    __shared__ ushort_t st[64 * 270];      // pad 256->270 shorts (odd-word row stride)
    int tid = threadIdx.x;
    int b = blockIdx.y, hw0 = blockIdx.x * 64;
    int lane = tid & 63, c4 = tid >> 6;
    int hw = hw0 + lane;
    int h = hw / WWD, w = hw - h * WWD;
    const float* xb = x + (b * CCH) * HWP + hw;
    float* xpd = ws + XP_OFF + (size_t)(b * CCH) * CHSTR + (h + 3) * XRW + (w + 3);
#pragma unroll 8
    for (int i = 0; i < 64; ++i) {
        int c = i * 4 + c4;
        float v = xb[c * HWP];
        st[lane * 270 + c] = f2bf(v);
        xpd[c * CHSTR] = v;
    }
    __syncthreads();
    const unsigned* stu = (const unsigned*)st;           // row stride 135 words
    unsigned* xtu = (unsigned*)(ws + XT_OFF);            // x_t rows: 128 words
    int rowg = b * HWP + hw0;
#pragma unroll
    for (int k = 0; k < 32; ++k) {
        int idx = k * 256 + tid;
        int row = idx >> 7, c2 = idx & 127;
        xtu[(rowg + row) * 128 + c2] = stu[row * 135 + c2];
    }
}

// ---------------------------------------------------------------------------
// conv1 (MFMA bf16): y_t[pix][64] = relu(bns[o]*(x_t @ W1^T)[o][pix] + bnt[o])
// ---------------------------------------------------------------------------
__global__ __launch_bounds__(256) void conv1_mfma(float* __restrict__ ws) {
    const ushort_t* xt  = (const ushort_t*)(ws + XT_OFF);
    const ushort_t* w1b = (const ushort_t*)(ws + W1B_OFF);
    const float* bns = ws + BNS_OFF;
    const float* bnt = ws + BNT_OFF;
    ushort_t* yt = (ushort_t*)(ws + YT_OFF);

    int tid = threadIdx.x, lane = tid & 63, wv = tid >> 6;
    int lr = lane & 15, lg = lane >> 4;
    int ot = blockIdx.x;                                  // 0..3
    int pixbase = blockIdx.y * 128 + wv * 32;

    const bf16x8* ap = (const bf16x8*)(w1b + (ot * 16 + lr) * CCH + lg * 8);
    bf16x8 a[8];
#pragma unroll
    for (int ks = 0; ks < 8; ++ks) a[ks] = ap[ks * 4];

    f32x4 acc[2] = {{0.f,0.f,0.f,0.f}, {0.f,0.f,0.f,0.f}};
#pragma unroll
    for (int f = 0; f < 2; ++f) {
        const bf16x8* bp = (const bf16x8*)(xt + (pixbase + f * 16 + lr) * CCH + lg * 8);
#pragma unroll
        for (int ks = 0; ks < 8; ++ks)
            acc[f] = __builtin_amdgcn_mfma_f32_16x16x32_bf16(a[ks], bp[ks * 4], acc[f], 0, 0, 0);
    }

    int o0 = ot * 16 + lg * 4;
    float4 s4 = *(const float4*)(bns + o0);
    float4 t4 = *(const float4*)(bnt + o0);
#pragma unroll
    for (int f = 0; f < 2; ++f) {
        int pix = pixbase + f * 16 + lr;
        union { ushort_t u[4]; uint2 v; } pk;
        pk.u[0] = f2bf(fmaxf(acc[f][0] * s4.x + t4.x, 0.f));
        pk.u[1] = f2bf(fmaxf(acc[f][1] * s4.y + t4.y, 0.f));
        pk.u[2] = f2bf(fmaxf(acc[f][2] * s4.z + t4.z, 0.f));
        pk.u[3] = f2bf(fmaxf(acc[f][3] * s4.w + t4.w, 0.f));
        *(uint2*)(yt + pix * CRD + o0) = pk.v;
    }
}

// ---------------------------------------------------------------------------
// invol_fused: per block (h0-tile of 4 rows, g, b):
//   A) stage y slice [224 pix][64] bf16 into swizzled LDS
//   B) MFMA: wgt tile (49 o2 x 224 pix) = W2[g-slice] @ y^T + b2 (in regs)
//   B2) scatter wgt -> LDS f32:
//       word = k*224 + wb*16 + ((r ^ ((wb>>1)&3) ^ ((k>>2)&3))&3)*4 + t
//       (reads: 16 wb-lanes -> distinct banks, wb+8 = 2-way free, c4 = broadcast)
//   C) involution, xr-major: per padded row load xv[12] via 3 ALIGNED dwordx4
//      (all-static indexing -> registers), FMA into acc2[r][t]
// ---------------------------------------------------------------------------
__global__ __launch_bounds__(256, 3) void invol_fused(const float* __restrict__ ws,
                                                      float* __restrict__ out) {
    __shared__ uint4 lds4[2744];           // 43904 B (y stage 28672 B; wl f32 43904 B)
    unsigned char* ldsb = (unsigned char*)lds4;

    int h0t = blockIdx.x;                  // 0..13
    int g   = blockIdx.y;
    int b   = blockIdx.z;
    int tid = threadIdx.x, lane = tid & 63, wv = tid >> 6;
    int lr = lane & 15, lg = lane >> 4;
    int pix0 = b * HWP + h0t * 224;

    // ---- Phase A: stage y (224 rows x 128 B), st_16x32-style swizzle
    const uint4* ysrc = (const uint4*)((const ushort_t*)(ws + YT_OFF) + (size_t)pix0 * CRD);
    for (int i = tid; i < 1792; i += 256) {
        int row = i >> 3;
        unsigned off = (unsigned)(i * 16) ^ (unsigned)((row & 7) << 4);
        *(uint4*)(ldsb + off) = ysrc[i];
    }
    __syncthreads();

    // ---- Phase B: MFMA. wave wv = o2-tile (rows wv*16..+15 of g-slice)
    const ushort_t* w2b = (const ushort_t*)(ws + W2B_OFF);
    const bf16x8* ar = (const bf16x8*)(w2b + (g * K2 + wv * 16 + lr) * CRD);
    bf16x8 a0 = ar[lg], a1 = ar[4 + lg];   // kstep 0 / 1

    f32x4 acc[14];
#pragma unroll
    for (int pt = 0; pt < 14; ++pt) acc[pt] = (f32x4){0.f, 0.f, 0.f, 0.f};
#pragma unroll
    for (int pt = 0; pt < 14; ++pt) {
        int row = pt * 16 + lr;
        unsigned sw = (unsigned)((row & 7) << 4);
        uint4 b0 = *(const uint4*)(ldsb + ((unsigned)(row * 128 + lg * 16) ^ sw));
        uint4 b1 = *(const uint4*)(ldsb + ((unsigned)(row * 128 + 64 + lg * 16) ^ sw));
        acc[pt] = __builtin_amdgcn_mfma_f32_16x16x32_bf16(a0, __builtin_bit_cast(bf16x8, b0), acc[pt], 0, 0, 0);
        acc[pt] = __builtin_amdgcn_mfma_f32_16x16x32_bf16(a1, __builtin_bit_cast(bf16x8, b1), acc[pt], 0, 0, 0);
    }
    __syncthreads();                        // y reads done; reuse LDS for wl

    // ---- Phase B2: scatter wgt -> wl f32 (swizzled, see header)
    float* wlf = (float*)ldsb;
    const float* b2p = ws + B2P_OFF;
    float b2v[4];
#pragma unroll
    for (int j = 0; j < 4; ++j)
        b2v[j] = b2p[g * K2 + wv * 16 + lg * 4 + j];   // padded, safe for k>=49
#pragma unroll
    for (int pt = 0; pt < 14; ++pt) {
        int pix = pt * 16 + lr;
        int r = pix / WWD;
        int w = pix - r * WWD;
        int wb = w >> 2, t = w & 3;
#pragma unroll
        for (int j = 0; j < 4; ++j) {
            int k = wv * 16 + lg * 4 + j;
            if (k < K2) {
                int f = (r ^ ((wb >> 1) & 3) ^ ((k >> 2) & 3)) & 3;
                wlf[k * 224 + wb * 16 + f * 4 + t] = acc[pt][j] + b2v[j];
            }
        }
    }
    __syncthreads();

    // ---- Phase C: lane = (c4, wb). ch = g*16 + wv*4 + c4; outputs 4r x 4w.
    int c4 = lane >> 4, wb = lane & 15;
    if (wb < 14) {
        int ch = g * GCN + wv * 4 + c4;
        const float* xrb = ws + XP_OFF + (size_t)(b * CCH + ch) * CHSTR
                         + (h0t * 4) * XRW + wb * 4;
        int wbs = (wb >> 1) & 3;
        const float* wbase = wlf + wb * 16;

        float acc2[4][4];
#pragma unroll
        for (int r = 0; r < 4; ++r)
#pragma unroll
            for (int t = 0; t < 4; ++t) acc2[r][t] = 0.f;

#pragma unroll
        for (int xr = 0; xr < 10; ++xr) {
            float xv[12];
            __builtin_memcpy(&xv[0], xrb + xr * XRW, 16);
            __builtin_memcpy(&xv[4], xrb + xr * XRW + 4, 16);
            __builtin_memcpy(&xv[8], xrb + xr * XRW + 8, 16);
#pragma unroll
            for (int ki = 0; ki < 7; ++ki) {
                int r = xr - ki;            // compile-time after unroll
                if (r >= 0 && r < 4) {
#pragma unroll
                    for (int dj = 0; dj < 7; ++dj) {
                        int k = ki * 7 + dj;
                        int fc = r ^ ((k >> 2) & 3);         // compile-time
                        f32x4 wr = *(const f32x4*)(wbase + k * 224 + (((fc ^ wbs) & 3) << 2));
#pragma unroll
                        for (int t = 0; t < 4; ++t)
                            acc2[r][t] = fmaf(xv[t + dj], wr[t], acc2[r][t]);
                    }
                }
            }
        }

        float* ob = out + (size_t)(b * CCH + ch) * HWP + (h0t * 4) * WWD + wb * 4;
#pragma unroll
        for (int r = 0; r < 4; ++r) {
            float4 v = {acc2[r][0], acc2[r][1], acc2[r][2], acc2[r][3]};
            *(float4*)(ob + r * WWD) = v;
        }
    }
}

// ---------------------------------------------------------------------------
extern "C" void kernel_launch(void* const* d_in, const int* in_sizes, int n_in,
                              void* d_out, int out_size, void* d_ws, size_t ws_size,
                              hipStream_t stream) {
    const float* x     = (const float*)d_in[0];
    const float* W1    = (const float*)d_in[1];
    const float* b1    = (const float*)d_in[2];
    const float* gamma = (const float*)d_in[3];
    const float* beta  = (const float*)d_in[4];
    const float* mean  = (const float*)d_in[5];
    const float* var   = (const float*)d_in[6];
    const float* W2    = (const float*)d_in[7];
    const float* b2    = (const float*)d_in[8];

    float* ws  = (float*)d_ws;
    float* out = (float*)d_out;

    prep_kernel<<<2048, 256, 0, stream>>>(W1, b1, gamma, beta, mean, var, W2, b2, ws);
    pack_x<<<dim3(HWP / 64, BB), 256, 0, stream>>>(x, ws);
    conv1_mfma<<<dim3(4, NPIX / 128), 256, 0, stream>>>(ws);
    invol_fused<<<dim3(14, NG, BB), 256, 0, stream>>>(ws, out);
}

// Round 7
// 74.927 us; speedup vs baseline: 1.3570x; 1.2408x over previous
//
#include <hip/hip_runtime.h>
#include <hip/hip_bf16.h>

// Problem constants
#define CCH   256        // channels C
#define NG    16         // groups
#define GCN   16         // group channels
#define CRD   64         // reduced channels C/R
#define HH    56
#define WWD   56
#define HWP   3136       // 56*56
#define BB    8
#define NPIX  25088      // B*H*W
#define K2    49
#define O2N   784        // K2 * NG
#define EPSV  1e-5f

#define XROWS 62         // 56 + 2*3 padded rows
#define XRW   64         // padded row width (16B-aligned rows; cols 0..61 valid)
#define CHSTR 3968       // 62*64 floats per (b,ch) plane

#define WLS   228        // wl per-k stride in floats (912 B; 4*228 % 32 == 16)

typedef unsigned short ushort_t;
typedef __attribute__((ext_vector_type(8))) short bf16x8;
typedef __attribute__((ext_vector_type(4))) float f32x4;

// workspace layout (float units)
#define XP_OFF   0                         // fp32 padded x [b][ch][62][64]
#define XP2_SZ   8126464                   // 8*256*3968
#define XT_OFF   8126464                   // x_t bf16 [pix][256]: 6,422,528 shorts
#define YT_OFF   11337728                  // y_t bf16 [pix][64]: 1,605,632 shorts
#define W1B_OFF  12140544                  // W1 bf16 [64][256]
#define W2B_OFF  12148736                  // W2 bf16 padded [800][64]
#define B2P_OFF  12174336                  // b2 padded: 800 floats
#define BNS_OFF  12175136                  // 64
#define BNT_OFF  12175200                  // 64
// end = 12,175,264 floats = 48.7 MB

__device__ __forceinline__ ushort_t f2bf(float f) {
    unsigned u = __builtin_bit_cast(unsigned, f);
    return (ushort_t)((u + 0x7FFFu + ((u >> 16) & 1u)) >> 16);   // RNE
}

// ---------------------------------------------------------------------------
// prep: zero xp; W1,W2(bf16, W2 padded to 800 rows); b2 padded; BN fold
// ---------------------------------------------------------------------------
__global__ __launch_bounds__(256) void prep_kernel(const float* __restrict__ W1,
                                                   const float* __restrict__ b1,
                                                   const float* __restrict__ gamma,
                                                   const float* __restrict__ beta,
                                                   const float* __restrict__ mean,
                                                   const float* __restrict__ var,
                                                   const float* __restrict__ W2,
                                                   const float* __restrict__ b2,
                                                   float* __restrict__ ws) {
    int gid = blockIdx.x * 256 + threadIdx.x;
    int stride = gridDim.x * 256;
    uint4 z = {0u, 0u, 0u, 0u};
    uint4* xpv = (uint4*)(ws + XP_OFF);
    for (int e = gid; e < XP2_SZ / 4; e += stride) xpv[e] = z;

    ushort_t* w1b = (ushort_t*)(ws + W1B_OFF);
    if (gid < CRD * CCH) w1b[gid] = f2bf(W1[gid]);               // [o][c]
    ushort_t* w2b = (ushort_t*)(ws + W2B_OFF);
    if (gid < 800 * CRD) w2b[gid] = (gid < O2N * CRD) ? f2bf(W2[gid]) : (ushort_t)0;
    if (gid < 800) ws[B2P_OFF + gid] = (gid < O2N) ? b2[gid] : 0.f;
    if (gid < CRD) {
        float s = gamma[gid] * rsqrtf(var[gid] + EPSV);
        ws[BNS_OFF + gid] = s;
        ws[BNT_OFF + gid] = (b1[gid] - mean[gid]) * s + beta[gid];
    }
}

// ---------------------------------------------------------------------------
// pack_x: read x ONCE -> x_t[pix][256] bf16 (LDS transpose) + xp fp32 interior
// ---------------------------------------------------------------------------
__global__ __launch_bounds__(256) void pack_x(const float* __restrict__ x,
                                              float* __restrict__ ws) {
    __shared__ ushort_t st[64 * 270];      // pad 256->270 shorts (odd-word row stride)
    int tid = threadIdx.x;
    int b = blockIdx.y, hw0 = blockIdx.x * 64;
    int lane = tid & 63, c4 = tid >> 6;
    int hw = hw0 + lane;
    int h = hw / WWD, w = hw - h * WWD;
    const float* xb = x + (b * CCH) * HWP + hw;
    float* xpd = ws + XP_OFF + (size_t)(b * CCH) * CHSTR + (h + 3) * XRW + (w + 3);
#pragma unroll 8
    for (int i = 0; i < 64; ++i) {
        int c = i * 4 + c4;
        float v = xb[c * HWP];
        st[lane * 270 + c] = f2bf(v);
        xpd[c * CHSTR] = v;
    }
    __syncthreads();
    const unsigned* stu = (const unsigned*)st;           // row stride 135 words
    unsigned* xtu = (unsigned*)(ws + XT_OFF);            // x_t rows: 128 words
    int rowg = b * HWP + hw0;
#pragma unroll
    for (int k = 0; k < 32; ++k) {
        int idx = k * 256 + tid;
        int row = idx >> 7, c2 = idx & 127;
        xtu[(rowg + row) * 128 + c2] = stu[row * 135 + c2];
    }
}

// ---------------------------------------------------------------------------
// conv1 (MFMA bf16): y_t[pix][64] = relu(bns[o]*(x_t @ W1^T)[o][pix] + bnt[o])
// ---------------------------------------------------------------------------
__global__ __launch_bounds__(256) void conv1_mfma(float* __restrict__ ws) {
    const ushort_t* xt  = (const ushort_t*)(ws + XT_OFF);
    const ushort_t* w1b = (const ushort_t*)(ws + W1B_OFF);
    const float* bns = ws + BNS_OFF;
    const float* bnt = ws + BNT_OFF;
    ushort_t* yt = (ushort_t*)(ws + YT_OFF);

    int tid = threadIdx.x, lane = tid & 63, wv = tid >> 6;
    int lr = lane & 15, lg = lane >> 4;
    int ot = blockIdx.x;                                  // 0..3
    int pixbase = blockIdx.y * 128 + wv * 32;

    const bf16x8* ap = (const bf16x8*)(w1b + (ot * 16 + lr) * CCH + lg * 8);
    bf16x8 a[8];
#pragma unroll
    for (int ks = 0; ks < 8; ++ks) a[ks] = ap[ks * 4];

    f32x4 acc[2] = {{0.f,0.f,0.f,0.f}, {0.f,0.f,0.f,0.f}};
#pragma unroll
    for (int f = 0; f < 2; ++f) {
        const bf16x8* bp = (const bf16x8*)(xt + (pixbase + f * 16 + lr) * CCH + lg * 8);
#pragma unroll
        for (int ks = 0; ks < 8; ++ks)
            acc[f] = __builtin_amdgcn_mfma_f32_16x16x32_bf16(a[ks], bp[ks * 4], acc[f], 0, 0, 0);
    }

    int o0 = ot * 16 + lg * 4;
    float4 s4 = *(const float4*)(bns + o0);
    float4 t4 = *(const float4*)(bnt + o0);
#pragma unroll
    for (int f = 0; f < 2; ++f) {
        int pix = pixbase + f * 16 + lr;
        union { ushort_t u[4]; uint2 v; } pk;
        pk.u[0] = f2bf(fmaxf(acc[f][0] * s4.x + t4.x, 0.f));
        pk.u[1] = f2bf(fmaxf(acc[f][1] * s4.y + t4.y, 0.f));
        pk.u[2] = f2bf(fmaxf(acc[f][2] * s4.z + t4.z, 0.f));
        pk.u[3] = f2bf(fmaxf(acc[f][3] * s4.w + t4.w, 0.f));
        *(uint2*)(yt + pix * CRD + o0) = pk.v;
    }
}

// ---------------------------------------------------------------------------
// invol_fused: per block (h0-tile of 4 rows, g, b):
//   A) stage y slice [224 pix][64] bf16 into swizzled LDS
//   B) MFMA: wgt tile (49 o2 x 224 pix) = W2[g-slice] @ y^T + b2 (in regs)
//   B2) scatter wgt -> LDS f32, layout wl[k][228]: word = k*228 + r*56 + w
//       (write banks 16lg+16pt+lr mod 32 => 2-way free; 912 B/k stride)
//   C) involution: lane=(c4,wb); reads = ONE base reg + static immediates
//      (4*228%32==16 layout), x rows via 3 aligned dwordx4 into NAMED f32x4
//      (no arrays, no runtime indices -> no scratch)
// ---------------------------------------------------------------------------
__global__ __launch_bounds__(256, 3) void invol_fused(const float* __restrict__ ws,
                                                      float* __restrict__ out) {
    __shared__ uint4 lds4[2794];           // 44704 B (y stage 28672 B; wl 44668 B)
    unsigned char* ldsb = (unsigned char*)lds4;

    int h0t = blockIdx.x;                  // 0..13
    int g   = blockIdx.y;
    int b   = blockIdx.z;
    int tid = threadIdx.x, lane = tid & 63, wv = tid >> 6;
    int lr = lane & 15, lg = lane >> 4;
    int pix0 = b * HWP + h0t * 224;

    // ---- Phase A: stage y (224 rows x 128 B), st_16x32-style swizzle
    const uint4* ysrc = (const uint4*)((const ushort_t*)(ws + YT_OFF) + (size_t)pix0 * CRD);
    for (int i = tid; i < 1792; i += 256) {
        int row = i >> 3;
        unsigned off = (unsigned)(i * 16) ^ (unsigned)((row & 7) << 4);
        *(uint4*)(ldsb + off) = ysrc[i];
    }
    __syncthreads();

    // ---- Phase B: MFMA. wave wv = o2-tile (rows wv*16..+15 of g-slice)
    const ushort_t* w2b = (const ushort_t*)(ws + W2B_OFF);
    const bf16x8* ar = (const bf16x8*)(w2b + (g * K2 + wv * 16 + lr) * CRD);
    bf16x8 a0 = ar[lg], a1 = ar[4 + lg];   // kstep 0 / 1

    f32x4 acc[14];
#pragma unroll
    for (int pt = 0; pt < 14; ++pt) acc[pt] = (f32x4){0.f, 0.f, 0.f, 0.f};
#pragma unroll
    for (int pt = 0; pt < 14; ++pt) {
        int row = pt * 16 + lr;
        unsigned sw = (unsigned)((row & 7) << 4);
        uint4 b0 = *(const uint4*)(ldsb + ((unsigned)(row * 128 + lg * 16) ^ sw));
        uint4 b1 = *(const uint4*)(ldsb + ((unsigned)(row * 128 + 64 + lg * 16) ^ sw));
        acc[pt] = __builtin_amdgcn_mfma_f32_16x16x32_bf16(a0, __builtin_bit_cast(bf16x8, b0), acc[pt], 0, 0, 0);
        acc[pt] = __builtin_amdgcn_mfma_f32_16x16x32_bf16(a1, __builtin_bit_cast(bf16x8, b1), acc[pt], 0, 0, 0);
    }
    __syncthreads();                        // y reads done; reuse LDS for wl

    // ---- Phase B2: scatter wgt -> wl f32, word = k*228 + r*56 + w
    float* wlf = (float*)ldsb;
    const float* b2p = ws + B2P_OFF;
    float b2v[4];
#pragma unroll
    for (int j = 0; j < 4; ++j)
        b2v[j] = b2p[g * K2 + wv * 16 + lg * 4 + j];   // padded, safe for k>=49
#pragma unroll
    for (int pt = 0; pt < 14; ++pt) {
        int pix = pt * 16 + lr;
        int r = pix / WWD;
        int w = pix - r * WWD;
#pragma unroll
        for (int j = 0; j < 4; ++j) {
            int k = wv * 16 + lg * 4 + j;
            if (k < K2)
                wlf[k * WLS + r * WWD + w] = acc[pt][j] + b2v[j];
        }
    }
    __syncthreads();

    // ---- Phase C: lane = (c4, wb). ch = g*16 + wv*4 + c4; outputs 4r x 4w.
    int c4 = lane >> 4, wb = lane & 15;
    if (wb < 14) {
        int ch = g * GCN + wv * 4 + c4;
        const float* xrb = ws + XP_OFF + (size_t)(b * CCH + ch) * CHSTR
                         + (h0t * 4) * XRW + wb * 4;
        const float* wbp = wlf + wb * 4;   // single LDS base; offsets static

        f32x4 acc2[4] = {{0.f,0.f,0.f,0.f},{0.f,0.f,0.f,0.f},
                         {0.f,0.f,0.f,0.f},{0.f,0.f,0.f,0.f}};

// element e (0..9) of the 12-float row window, from named vectors
#define XVe(e) ((e) < 4 ? xu[(e) & 3] : ((e) < 8 ? xm[(e) & 3] : xq[(e) & 3]))
#pragma unroll
        for (int xr = 0; xr < 10; ++xr) {
            f32x4 xu, xm, xq;
            __builtin_memcpy(&xu, xrb + xr * XRW, 16);
            __builtin_memcpy(&xm, xrb + xr * XRW + 4, 16);
            __builtin_memcpy(&xq, xrb + xr * XRW + 8, 16);
#pragma unroll
            for (int ki = 0; ki < 7; ++ki) {
                int r = xr - ki;            // compile-time after unroll
                if (r >= 0 && r < 4) {
#pragma unroll
                    for (int dj = 0; dj < 7; ++dj) {
                        int k = ki * 7 + dj;
                        f32x4 wr = *(const f32x4*)(wbp + k * WLS + r * WWD);
#pragma unroll
                        for (int t = 0; t < 4; ++t)
                            acc2[r][t] = fmaf(XVe(t + dj), wr[t], acc2[r][t]);
                    }
                }
            }
        }
#undef XVe

        float* ob = out + (size_t)(b * CCH + ch) * HWP + (h0t * 4) * WWD + wb * 4;
#pragma unroll
        for (int r = 0; r < 4; ++r) {
            float4 v = {acc2[r][0], acc2[r][1], acc2[r][2], acc2[r][3]};
            *(float4*)(ob + r * WWD) = v;
        }
    }
}

// ---------------------------------------------------------------------------
extern "C" void kernel_launch(void* const* d_in, const int* in_sizes, int n_in,
                              void* d_out, int out_size, void* d_ws, size_t ws_size,
                              hipStream_t stream) {
    const float* x     = (const float*)d_in[0];
    const float* W1    = (const float*)d_in[1];
    const float* b1    = (const float*)d_in[2];
    const float* gamma = (const float*)d_in[3];
    const float* beta  = (const float*)d_in[4];
    const float* mean  = (const float*)d_in[5];
    const float* var   = (const float*)d_in[6];
    const float* W2    = (const float*)d_in[7];
    const float* b2    = (const float*)d_in[8];

    float* ws  = (float*)d_ws;
    float* out = (float*)d_out;

    prep_kernel<<<2048, 256, 0, stream>>>(W1, b1, gamma, beta, mean, var, W2, b2, ws);
    pack_x<<<dim3(HWP / 64, BB), 256, 0, stream>>>(x, ws);
    conv1_mfma<<<dim3(4, NPIX / 128), 256, 0, stream>>>(ws);
    invol_fused<<<dim3(14, NG, BB), 256, 0, stream>>>(ws, out);
}